// Round 5
// baseline (180.256 us; speedup 1.0000x reference)
//
#include <hip/hip_runtime.h>
#include <math.h>

#define HH 192
#define WW 192
#define CC 64
#define CHW (HH*WW)
#define SS 16
#define NB 12
#define NBLK 144
#define NSH 49
#define UROW 22          // union region rows
#define RW 24            // region row elems staged (16B-aligned from cbase4)
#define RDW 13           // dwords per packed bf16 copy-row (12 data + 1 pad)
#define NCHK 2           // channels per chunk (1 MFMA K-step)
#define NCHUNK 8         // chunks per wave -> 16 channels/wave
#define NT 10            // N-tiles of 16 covering 154 (yw,o) columns
#define LN 160           // S row stride
#define CSTRIDE (UROW*2*RDW)   // 572 dw per channel in region slice
#define REGDW (NCHK*CSTRIDE)   // 1144 dw region per wave
// overlay offsets (dwords, from LDS base; valid after region is dead)
#define S0   0
#define RS0  (16*LN)           // 2560
#define CS0  (RS0 + UROW*RW)   // 2560+528 = 3088
#define ASUM0 (CS0 + 154)      // 3242
#define OVL_N (ASUM0 + 1)      // 3243 floats to zero
#define LDS_DW (4*REGDW)       // 4576 dwords = 18304 B

typedef __attribute__((ext_vector_type(4))) float f32x4;
typedef __attribute__((ext_vector_type(8))) short bf16x8;

__device__ __forceinline__ int iclamp(int v, int lo, int hi){ return v<lo?lo:(v>hi?hi:v); }

// round-to-nearest-even float -> bf16 (as u16 in low bits)
__device__ __forceinline__ unsigned f2bf(float f){
  unsigned u = __float_as_uint(f);
  return (u + 0x7FFFu + ((u >> 16) & 1u)) >> 16;
}
__device__ __forceinline__ unsigned pk2(float lo, float hi){
  return f2bf(lo) | (f2bf(hi) << 16);
}

__global__ __launch_bounds__(256, 4) void dist_kernel(
    const float* __restrict__ fm1, const float* __restrict__ fm2,
    float* __restrict__ scratch)
{
  __shared__ unsigned smu[LDS_DW];
  float* smf = (float*)smu;

  const int blk = blockIdx.x;           // 0..143
  const int b   = blockIdx.y;           // 0..7
  const int by  = blk / NB, bx = blk - by*NB;
  const int ys  = by*SS, xs = bx*SS;
  const int rbase = iclamp(ys-3, 0, HH-UROW);
  const int ey = (ys-3) - rbase;        // {-3..3} effective: {-3,0,3}
  const int cbase  = iclamp(xs-3, 0, WW-UROW);
  const int cbase4 = (bx == 0) ? 0 : ((bx == NB-1) ? (WW-RW) : (xs-4));
  const int OX = cbase - cbase4;        // 0/1/2
  const int ex = (xs-3) - cbase;        // -3/0/3

  const int tid  = threadIdx.x;
  const int wid  = tid >> 6;
  const int lane = tid & 63;
  const int row16 = lane & 15;          // A: y row / B: n within tile
  const int kb    = lane >> 4;          // 0..3 k-block
  const int coff  = lane >> 5;          // channel offset within K-step (0..1)
  const int x0    = ((lane >> 4) & 1) * 8;

  const int c0w = wid * (NCHK*NCHUNK);  // wave's channel base (0,16,32,48)
  const int regbase = wid * REGDW;

  const float* f1b = fm1 + (size_t)b*CC*CHW;
  const float* f2b = fm2 + (size_t)b*CC*CHW;

  // ---- per-lane B-fragment LDS dword bases per N-tile (chunk-invariant)
  int boff[NT];
#pragma unroll
  for (int nt = 0; nt < NT; ++nt) {
    int n  = nt*16 + row16;
    int n7 = n / 7;
    int o  = n - n7*7;
    int yw = n7 > (UROW-1) ? (UROW-1) : n7;
    int e  = OX + o + x0;               // elem offset in 24-wide region row
    int p  = e & 1;
    int d0 = (e - p) >> 1;
    boff[nt] = regbase + ((coff*UROW + yw)*2 + p)*RDW + d0;
  }

  // ---- staging position assignment (static per lane; 264 float2-pairs per ch)
  int pyw[5], pdp[5];
#pragma unroll
  for (int i = 0; i < 5; ++i) {
    int pi = lane + 64*i;
    int piq = (pi < 264) ? pi : 0;
    pyw[i] = piq / 12;
    pdp[i] = piq - 12*pyw[i];
  }
  const int aoff = (ys + row16)*WW + xs + x0;

  f32x4 acc[NT];
#pragma unroll
  for (int nt = 0; nt < NT; ++nt) acc[nt] = (f32x4){0.f,0.f,0.f,0.f};
  float rsa[5] = {0.f,0.f,0.f,0.f,0.f};
  float rsb[5] = {0.f,0.f,0.f,0.f,0.f};
  float asum = 0.f;

  // ================= main chunk loop (wave-private, no barriers) =========
  for (int ck = 0; ck < NCHUNK; ++ck) {
    const float* f2c = f2b + (size_t)(c0w + ck*NCHK)*CHW;
    // ---- stage 2 channels of 22x24 region as 2 parity-packed bf16 copies
#pragma unroll
    for (int i = 0; i < 5; ++i) {
      if (i < 4 || lane < 8) {
        const int go = (rbase + pyw[i])*WW + cbase4 + 2*pdp[i];
        const int wo = regbase + (pyw[i]*2)*RDW + pdp[i];
#pragma unroll
        for (int ch = 0; ch < NCHK; ++ch) {
          const float* g = f2c + (size_t)ch*CHW + go;
          float vx = g[0], vy = g[1];
          float e2 = (pdp[i] < 11) ? g[2] : 0.f;
          smu[wo + ch*CSTRIDE]       = pk2(vx, vy);   // copy0: elems (2d,2d+1)
          smu[wo + ch*CSTRIDE + RDW] = pk2(vy, e2);   // copy1: elems (2d+1,2d+2)
          rsa[i] = fmaf(vx, vx, rsa[i]);
          rsb[i] = fmaf(vy, vy, rsb[i]);
        }
      }
    }
    asm volatile("s_waitcnt lgkmcnt(0)" ::: "memory");
    __builtin_amdgcn_sched_barrier(0);

    // ---- A fragment: template rows from global (L1/L2-resident), cvt bf16
    const float* ap = f1b + (size_t)(c0w + ck*NCHK + coff)*CHW + aoff;
    float4 a0 = *(const float4*)ap;
    float4 a1 = *(const float4*)(ap + 4);
    asum = fmaf(a0.x,a0.x, fmaf(a0.y,a0.y, fmaf(a0.z,a0.z, fmaf(a0.w,a0.w, asum))));
    asum = fmaf(a1.x,a1.x, fmaf(a1.y,a1.y, fmaf(a1.z,a1.z, fmaf(a1.w,a1.w, asum))));
    union { unsigned u[4]; bf16x8 v; } A_;
    A_.u[0] = pk2(a0.x, a0.y); A_.u[1] = pk2(a0.z, a0.w);
    A_.u[2] = pk2(a1.x, a1.y); A_.u[3] = pk2(a1.z, a1.w);

    // ---- 10 N-tiles, one K-step each
#pragma unroll
    for (int nt = 0; nt < NT; ++nt) {
      const unsigned* bp = smu + boff[nt];
      union { unsigned u[4]; bf16x8 v; } B_;
      B_.u[0] = bp[0]; B_.u[1] = bp[1]; B_.u[2] = bp[2]; B_.u[3] = bp[3];
      acc[nt] = __builtin_amdgcn_mfma_f32_16x16x32_bf16(A_.v, B_.v, acc[nt], 0, 0, 0);
    }
  }

  // ================= merge phase =========================================
  __syncthreads();                       // region dead from here; overlay S/RS
  for (int i = tid; i < OVL_N; i += 256) smf[i] = 0.f;
  __syncthreads();

  // S[y][n] merge: C layout col=lane&15 (n), row=(lane>>4)*4+reg (y)
#pragma unroll
  for (int nt = 0; nt < NT; ++nt) {
#pragma unroll
    for (int r = 0; r < 4; ++r) {
      atomicAdd(&smf[S0 + (kb*4 + r)*LN + nt*16 + row16], acc[nt][r]);
    }
  }
  // RS merge (sum over channels of w^2 per region position)
#pragma unroll
  for (int i = 0; i < 5; ++i) {
    if (i < 4 || lane < 8) {
      atomicAdd(&smf[RS0 + pyw[i]*RW + 2*pdp[i]    ], rsa[i]);
      atomicAdd(&smf[RS0 + pyw[i]*RW + 2*pdp[i] + 1], rsb[i]);
    }
  }
  // asum merge
  {
    float v = asum;
#pragma unroll
    for (int off = 32; off; off >>= 1) v += __shfl_xor(v, off);
    if (lane == 0) atomicAdd(&smf[ASUM0], v);
  }
  __syncthreads();

  // ---- CS[yw][o]: sliding 16-window sums of RS along x
  if (tid < 154) {
    int yw = tid / 7, o = tid - 7*yw;
    float s = 0.f;
#pragma unroll
    for (int x = 0; x < 16; ++x) s += smf[RS0 + yw*RW + OX + o + x];
    smf[CS0 + tid] = s;
  }
  __syncthreads();

  // ---- distances + min (wave 0)
  if (tid < 64) {
    int tu = tid < NSH ? tid : NSH-1;
    int t = tu / 7, u = tu - 7*t;
    int oyt = iclamp(t + ey, 0, 6);
    int o   = iclamp(u + ex, 0, 6);
    float s = smf[ASUM0];
#pragma unroll
    for (int y = 0; y < 16; ++y) {
      int n = (y + oyt)*7 + o;
      s += smf[CS0 + n] - 2.f*smf[S0 + y*LN + n];
    }
#pragma unroll
    for (int off = 32; off; off >>= 1) s = fminf(s, __shfl_xor(s, off));
    if (tid == 0) scratch[(size_t)b*NBLK + blk] = s;   // raw min
  }
}

__global__ void topk_kernel(const float* __restrict__ scratch, float* __restrict__ out)
{
  const int b = blockIdx.x;            // 0..7
  const int lane = threadIdx.x;        // 0..63
  const float INF = __builtin_inff();

  const float* p = scratch + (size_t)b*NBLK;
  float v0 = p[lane];
  float v1 = p[lane + 64];
  float v2 = (lane < 16) ? p[lane + 128] : INF;

  float sum = 0.f;
  for (int it = 0; it < 16; ++it) {
    float lm = fminf(v0, fminf(v1, v2));
    float m = lm;
#pragma unroll
    for (int off = 32; off; off >>= 1) m = fminf(m, __shfl_xor(m, off));
    sum += m;
    unsigned long long mask = __ballot(lm == m);
    int leader = __ffsll(mask) - 1;
    if (lane == leader) {
      if (v0 == m)      v0 = INF;
      else if (v1 == m) v1 = INF;
      else              v2 = INF;
    }
  }
  if (lane == 0) out[b] = sum * (1.0f/((float)CC*SS*SS));
}

extern "C" void kernel_launch(void* const* d_in, const int* in_sizes, int n_in,
                              void* d_out, int out_size, void* d_ws, size_t ws_size,
                              hipStream_t stream)
{
  const float* fm1 = (const float*)d_in[0];
  const float* fm2 = (const float*)d_in[1];
  float* out  = (float*)d_out;
  float* scratch = (float*)d_ws;       // 8*144 floats

  dist_kernel<<<dim3(NBLK, 8), 256, 0, stream>>>(fm1, fm2, scratch);
  topk_kernel<<<8, 64, 0, stream>>>(scratch, out);
}